// Round 6
// baseline (312.656 us; speedup 1.0000x reference)
//
#include <hip/hip_runtime.h>
#include <math.h>

typedef __bf16 bf16x8 __attribute__((ext_vector_type(8)));
typedef __bf16 bf16x4 __attribute__((ext_vector_type(4)));
typedef float  f32x4  __attribute__((ext_vector_type(4)));

// lgkmcnt(0) only: vmcnt=63 (bits[3:0]=0xF,[15:14]=0x3), expcnt=7, lgkmcnt=0
#define WAIT_LGKM0() __builtin_amdgcn_s_waitcnt(0xC07F)

// ---------------------------------------------------------------------------
// cvt: fp32 -> bf16 for the 4 weight matrices (512x512 each)
// ---------------------------------------------------------------------------
__global__ __launch_bounds__(256)
void cvt_w(const float* __restrict__ w0, const float* __restrict__ w1,
           const float* __restrict__ w2, const float* __restrict__ w3,
           __bf16* __restrict__ d0, __bf16* __restrict__ d1,
           __bf16* __restrict__ d2, __bf16* __restrict__ d3)
{
    const int y = blockIdx.y;
    const float* s = (y == 0) ? w0 : (y == 1) ? w1 : (y == 2) ? w2 : w3;
    __bf16*      d = (y == 0) ? d0 : (y == 1) ? d1 : (y == 2) ? d2 : d3;
    const int i = blockIdx.x * 256 + threadIdx.x;
    float4 a = *(const float4*)(s + (size_t)i * 8);
    float4 b = *(const float4*)(s + (size_t)i * 8 + 4);
    bf16x8 v;
    v[0] = (__bf16)a.x; v[1] = (__bf16)a.y; v[2] = (__bf16)a.z; v[3] = (__bf16)a.w;
    v[4] = (__bf16)b.x; v[5] = (__bf16)b.y; v[6] = (__bf16)b.z; v[7] = (__bf16)b.w;
    *(bf16x8*)(d + (size_t)i * 8) = v;
}

// ---------------------------------------------------------------------------
// Fused QKV projection. X fp32 (cvt on load), W bf16. Tile 64(M)x128(N).
// ---------------------------------------------------------------------------
__global__ __launch_bounds__(256)
void qkv_proj(const float* __restrict__ X,
              const __bf16* __restrict__ Wqb, const __bf16* __restrict__ Wkb,
              const __bf16* __restrict__ Wvb,
              const float* __restrict__ bq, const float* __restrict__ bk,
              const float* __restrict__ bv,
              __bf16* __restrict__ qTb, __bf16* __restrict__ kTb,
              __bf16* __restrict__ vTb)
{
    const int z = blockIdx.z;
    const __bf16* Wb   = (z == 0) ? Wqb : (z == 1) ? Wkb : Wvb;
    const float*  bias = (z == 0) ? bq  : (z == 1) ? bk  : bv;

    const int tid  = threadIdx.x;
    const int w    = tid >> 6;
    const int lane = tid & 63;
    const int lq   = lane & 15;
    const int quad = lane >> 4;
    const int n0    = blockIdx.x * 64 + (w >> 1) * 32;
    const int obase = blockIdx.y * 128 + (w & 1) * 64;

    f32x4 acc[2][4] = {};
#pragma unroll 2
    for (int k0 = 0; k0 < 512; k0 += 32) {
        bf16x8 af[2], bfr[4];
#pragma unroll
        for (int m = 0; m < 2; m++) {
            const float* xp = X + (size_t)(n0 + m * 16 + lq) * 512 + k0 + quad * 8;
            float4 x0 = *(const float4*)xp;
            float4 x1 = *(const float4*)(xp + 4);
            bf16x8 v;
            v[0] = (__bf16)x0.x; v[1] = (__bf16)x0.y; v[2] = (__bf16)x0.z; v[3] = (__bf16)x0.w;
            v[4] = (__bf16)x1.x; v[5] = (__bf16)x1.y; v[6] = (__bf16)x1.z; v[7] = (__bf16)x1.w;
            af[m] = v;
        }
#pragma unroll
        for (int nn = 0; nn < 4; nn++)
            bfr[nn] = *(const bf16x8*)(Wb + (size_t)(obase + nn * 16 + lq) * 512 + k0 + quad * 8);
#pragma unroll
        for (int m = 0; m < 2; m++)
#pragma unroll
            for (int nn = 0; nn < 4; nn++)
                acc[m][nn] = __builtin_amdgcn_mfma_f32_16x16x32_bf16(af[m], bfr[nn], acc[m][nn], 0, 0, 0);
    }

    const float scaling = 0.17677669529663687f;
#pragma unroll
    for (int m = 0; m < 2; m++)
#pragma unroll
        for (int nn = 0; nn < 4; nn++)
#pragma unroll
            for (int r = 0; r < 4; r++) {
                const int n = n0 + m * 16 + quad * 4 + r;
                const int o = obase + nn * 16 + lq;
                float val = acc[m][nn][r] + bias[o];
                const int t = n >> 2, b = n & 3;
                const int h = o >> 5, d = o & 31;
                const int bh = b * 16 + h;
                if (z == 0)
                    qTb[(((size_t)bh * 1024 + t) << 5) + d] = (__bf16)(val * scaling);
                else if (z == 1)
                    kTb[(((size_t)bh * 1024 + t) << 5) + d] = (__bf16)val;
                else
                    vTb[(((size_t)bh * 32 + d) << 10) + t] = (__bf16)val;
            }
}

// ---------------------------------------------------------------------------
// Out projection: A bf16 [4096][512], W bf16, out fp32 + bias. Tile 64x128.
// ---------------------------------------------------------------------------
__global__ __launch_bounds__(256)
void out_proj(const __bf16* __restrict__ A, const __bf16* __restrict__ Wb,
              const float* __restrict__ bias, float* __restrict__ out)
{
    const int tid  = threadIdx.x;
    const int w    = tid >> 6;
    const int lane = tid & 63;
    const int lq   = lane & 15;
    const int quad = lane >> 4;
    const int n0    = blockIdx.x * 64 + (w >> 1) * 32;
    const int obase = blockIdx.y * 128 + (w & 1) * 64;

    f32x4 acc[2][4] = {};
#pragma unroll 2
    for (int k0 = 0; k0 < 512; k0 += 32) {
        bf16x8 af[2], bfr[4];
#pragma unroll
        for (int m = 0; m < 2; m++)
            af[m] = *(const bf16x8*)(A + (size_t)(n0 + m * 16 + lq) * 512 + k0 + quad * 8);
#pragma unroll
        for (int nn = 0; nn < 4; nn++)
            bfr[nn] = *(const bf16x8*)(Wb + (size_t)(obase + nn * 16 + lq) * 512 + k0 + quad * 8);
#pragma unroll
        for (int m = 0; m < 2; m++)
#pragma unroll
            for (int nn = 0; nn < 4; nn++)
                acc[m][nn] = __builtin_amdgcn_mfma_f32_16x16x32_bf16(af[m], bfr[nn], acc[m][nn], 0, 0, 0);
    }
#pragma unroll
    for (int m = 0; m < 2; m++)
#pragma unroll
        for (int nn = 0; nn < 4; nn++)
#pragma unroll
            for (int r = 0; r < 4; r++) {
                const int n = n0 + m * 16 + quad * 4 + r;
                const int o = obase + nn * 16 + lq;
                out[(size_t)n * 512 + o] = acc[m][nn][r] + bias[o];
            }
}

// ---------------------------------------------------------------------------
// MFMA attention, K/V-reuse build. Block = (32 t-rows, b, 8-head half).
// Grid (32,4,2) = 256 blocks = 1/CU, 8 waves, wave w owns s [w*128,+128).
//
// THE POINT OF THIS ROUND: byte volume. Previously every 16-row block
// re-read K/V per head -> 512 MB of K/V issue on top of the 256 MB bias
// stream; the kernel sat at the memory-side BW ceiling (~790 MB / ~140us),
// which is why scheduling (R3), cache placement (R4) and occupancy (R5)
// were all null. Here each block covers TWO 16-row t-subtiles and loads
// K/V for a head ONCE into registers, reusing them for both subtiles:
// K/V issue halves (512 -> 256 MB). 16 iterations (8 heads x 2 ts) keep
// the exact per-iteration stream profile of the proven loop: qa+cj
// register prefetch (youngest VMEM), K-wait leaves V+prefetch in flight,
// PV all-register V, lgkm-only raw barrier, Op/red double-buffer.
// avg_reg becomes [2][32] (+32 VGPR, ~230 total, under the 256 cap).
// ---------------------------------------------------------------------------
__global__ __launch_bounds__(512, 2)
void attn_mfma(const __bf16* __restrict__ qTb, const __bf16* __restrict__ kTb,
               const __bf16* __restrict__ vTb, const float* __restrict__ bias,
               const int* __restrict__ mask, __bf16* __restrict__ attnb,
               float* __restrict__ avgf, __bf16* __restrict__ p1)
{
    // [0,8448): Op[2][8][528]  [8448,8704): red[2][8][16]
    // [8704,17408): P bf16 [8][16*136]
    __shared__ float smem[17408];
    float* const Op0  = smem;
    float* const red0 = &smem[8448];
    __bf16* const Pbase = (__bf16*)&smem[8704];

    const int tid  = threadIdx.x;
    const int w    = tid >> 6;
    const int lane = tid & 63;
    const int lq   = lane & 15;
    const int quad = lane >> 4;

    // bijective XCD swizzle. Natural dispatch round-robins bid across the 8
    // XCDs; swz gives XCD k the contiguous chunk [32k,32k+32) = one (z,b)
    // pair x all 32 t-supertiles -> per-XCD hot K/V = 8 heads x 1 batch
    // = 1 MB (fits the 4 MB L2); bias share 32 MB streams through.
    const int bid = blockIdx.z * 128 + blockIdx.y * 32 + blockIdx.x;
    const int swz = (bid & 7) * 32 + (bid >> 3);
    const int t0  = (swz & 31) * 32;       // 32-row t-supertile
    const int b   = (swz >> 5) & 3;
    const int z   = swz >> 7;              // head half
    const int sbase = w * 128;

    __bf16* const Pw = Pbase + w * 2176;   // 16*136 bf16 per wave

    // pack 32 mask bits (s = sbase + j*16 + quad*4 + r) -- s-only, shared
    // by both t-subtiles
    unsigned mbits = 0;
    {
        const int* mp = mask + b * 1024 + sbase + quad * 4;
#pragma unroll
        for (int j = 0; j < 8; j++) {
            int4 m4 = *(const int4*)(mp + j * 16);
            mbits |= (unsigned)(m4.x != 0) << (j * 4 + 0);
            mbits |= (unsigned)(m4.y != 0) << (j * 4 + 1);
            mbits |= (unsigned)(m4.z != 0) << (j * 4 + 2);
            mbits |= (unsigned)(m4.w != 0) << (j * 4 + 3);
        }
    }

    // bases for this block's 8 heads (z*8 .. z*8+7), t-rows t0..t0+31
    const float* const bb = bias + (((size_t)(b * 16 + z * 8)) << 20) +
                            (((size_t)(t0 + lq)) << 10) + sbase + quad * 4;
    const __bf16* const qp0 = qTb + (((size_t)((b * 16 + z * 8) * 1024 + t0)) << 5) +
                              lq * 32 + quad * 8;
    const __bf16* const kp0 = kTb + ((size_t)(b * 16 + z * 8) << 15);
    const __bf16* const vp0 = vTb + ((size_t)(b * 16 + z * 8) << 15);

    // prologue: (head 0, ts 0) Q + bias into registers
    bf16x8 qa = *(const bf16x8*)qp0;
    f32x4 cj[8];
#pragma unroll
    for (int j = 0; j < 8; j++) cj[j] = *(const f32x4*)(bb + j * 16);

    float avg_reg[2][32] = {};
    bf16x8 kb[8];            // persist across the two t-subtiles of a head
    bf16x8 v0r[4], v1r[4];

#pragma unroll
    for (int i = 0; i < 16; i++) {
        const int hh = i >> 1;          // head within the half
        const int ts = i & 1;           // t-subtile (16 rows)
        float* const Op  = Op0  + (i & 1) * 4224;
        float* const red = red0 + (i & 1) * 128;

        // K/V for this head: loaded once (ts==0), reused at ts==1.
        if (ts == 0) {
            const __bf16* kp = kp0 + ((size_t)hh << 15);
            const __bf16* vp = vp0 + ((size_t)hh << 15);
#pragma unroll
            for (int j = 0; j < 8; j++)
                kb[j] = *(const bf16x8*)(kp + (size_t)(sbase + j * 16 + lq) * 32 + quad * 8);
#pragma unroll
            for (int ks = 0; ks < 4; ks++) {
                v0r[ks] = *(const bf16x8*)(vp + (size_t)lq * 1024 + sbase + ks * 32 + quad * 8);
                v1r[ks] = *(const bf16x8*)(vp + (size_t)(16 + lq) * 1024 + sbase + ks * 32 + quad * 8);
            }
        }
        __builtin_amdgcn_sched_barrier(0);

        // QK: kb/qa waits leave (younger) V + stream prefetch outstanding
        f32x4 acc[8];
        __builtin_amdgcn_s_setprio(1);
#pragma unroll
        for (int j = 0; j < 8; j++)
            acc[j] = __builtin_amdgcn_mfma_f32_16x16x32_bf16(kb[j], qa, cj[j], 0, 0, 0);
        __builtin_amdgcn_s_setprio(0);
        __builtin_amdgcn_sched_barrier(0);

        // prefetch next iteration's Q + bias (youngest VMEM; wraps benignly)
        {
            const int in  = (i + 1) & 15;
            const int hn  = in >> 1;
            const int tsn = in & 1;
            qa = *(const bf16x8*)(qp0 + ((size_t)hn << 15) + (tsn << 9));
            const float* bn = bb + ((size_t)hn << 20) + (tsn << 14);
#pragma unroll
            for (int j = 0; j < 8; j++) cj[j] = *(const f32x4*)(bn + j * 16);
        }
        __builtin_amdgcn_sched_barrier(0);

        // exp (no max pass; scores bounded) + mask + row partial sum
        float sm = 0.f;
#pragma unroll
        for (int j = 0; j < 8; j++)
#pragma unroll
            for (int r = 0; r < 4; r++) {
                float p = __expf(acc[j][r]);
                p = ((mbits >> (j * 4 + r)) & 1u) ? 0.f : p;
                acc[j][r] = p;
                sm += p;
            }
        sm += __shfl_xor(sm, 16);
        sm += __shfl_xor(sm, 32);

        // unnormalized bf16 P into per-wave LDS region (same-wave use only)
#pragma unroll
        for (int j = 0; j < 8; j++) {
            bf16x4 pv;
            pv[0] = (__bf16)acc[j][0]; pv[1] = (__bf16)acc[j][1];
            pv[2] = (__bf16)acc[j][2]; pv[3] = (__bf16)acc[j][3];
            *(bf16x4*)&Pw[lq * 136 + j * 16 + quad * 4] = pv;
        }
        if (lane < 16) red[w * 16 + lane] = sm;

        // PV: P from LDS (lgkmcnt only), V already in registers
        f32x4 o0 = {0.f, 0.f, 0.f, 0.f}, o1 = {0.f, 0.f, 0.f, 0.f};
        __builtin_amdgcn_s_setprio(1);
#pragma unroll
        for (int ks = 0; ks < 4; ks++) {
            bf16x8 pa = *(const bf16x8*)&Pw[lq * 136 + ks * 32 + quad * 8];
            o0 = __builtin_amdgcn_mfma_f32_16x16x32_bf16(pa, v0r[ks], o0, 0, 0, 0);
            o1 = __builtin_amdgcn_mfma_f32_16x16x32_bf16(pa, v1r[ks], o1, 0, 0, 0);
        }
        __builtin_amdgcn_s_setprio(0);
#pragma unroll
        for (int r = 0; r < 4; r++) {
            Op[w * 528 + (quad * 4 + r) * 33 + lq]      = o0[r];
            Op[w * 528 + (quad * 4 + r) * 33 + 16 + lq] = o1[r];
        }

        // raw barrier: compiler fence + lgkm-only drain; prefetch stays live.
        __builtin_amdgcn_sched_barrier(0);
        asm volatile("" ::: "memory");
        WAIT_LGKM0();
        __builtin_amdgcn_s_barrier();
        asm volatile("" ::: "memory");
        __builtin_amdgcn_sched_barrier(0);

        // cross-wave reduce: normalized O write
        {
            const int t = tid >> 5, d = tid & 31;
            float s = 0.f, o = 0.f;
#pragma unroll
            for (int w2 = 0; w2 < 8; w2++) s += red[w2 * 16 + t];
#pragma unroll
            for (int w2 = 0; w2 < 8; w2++) o += Op[w2 * 528 + t * 33 + d];
            attnb[((size_t)(t0 + ts * 16 + t) * 4 + b) * 512 + (z * 8 + hh) * 32 + d] =
                (__bf16)(o / s);
        }

        // inv for this lane's rows (t = ts*16+lq) + avg fold into this
        // t-subtile's accumulator; acc dies here
        float s_all = 0.f;
#pragma unroll
        for (int w2 = 0; w2 < 8; w2++) s_all += red[w2 * 16 + lq];
        const float inv = 1.0f / s_all;
#pragma unroll
        for (int j = 0; j < 8; j++)
#pragma unroll
            for (int r = 0; r < 4; r++)
                avg_reg[ts][j * 4 + r] += acc[j][r] * inv;
    }

    // head-mean stores for both t-subtiles: z=0 fp32 direct, z=1 bf16 partial
#pragma unroll
    for (int ts = 0; ts < 2; ts++) {
        const size_t rowbase = ((size_t)(b * 1024 + t0 + ts * 16 + lq) << 10) +
                               sbase + quad * 4;
        if (z == 0) {
            float* ap = avgf + rowbase;
#pragma unroll
            for (int j = 0; j < 8; j++) {
                f32x4 v = { avg_reg[ts][j * 4 + 0] * 0.0625f,
                            avg_reg[ts][j * 4 + 1] * 0.0625f,
                            avg_reg[ts][j * 4 + 2] * 0.0625f,
                            avg_reg[ts][j * 4 + 3] * 0.0625f };
                *(f32x4*)(ap + j * 16) = v;
            }
        } else {
            __bf16* pp = p1 + rowbase;
#pragma unroll
            for (int j = 0; j < 8; j++) {
                bf16x4 v;
                v[0] = (__bf16)(avg_reg[ts][j * 4 + 0] * 0.0625f);
                v[1] = (__bf16)(avg_reg[ts][j * 4 + 1] * 0.0625f);
                v[2] = (__bf16)(avg_reg[ts][j * 4 + 2] * 0.0625f);
                v[3] = (__bf16)(avg_reg[ts][j * 4 + 3] * 0.0625f);
                *(bf16x4*)(pp + j * 16) = v;
            }
        }
    }
}

// avg_out += p1 (bf16 partial). 2048 blocks * 256 thr * 8 = 4194304
__global__ __launch_bounds__(256)
void avg_add(float* __restrict__ avg, const __bf16* __restrict__ p1)
{
    const size_t i = ((size_t)blockIdx.x * 256 + threadIdx.x) * 8;
    bf16x8 a = *(const bf16x8*)(p1 + i);
    float4 lo = *(float4*)(avg + i);
    float4 hi = *(float4*)(avg + i + 4);
    lo.x += (float)a[0]; lo.y += (float)a[1];
    lo.z += (float)a[2]; lo.w += (float)a[3];
    hi.x += (float)a[4]; hi.y += (float)a[5];
    hi.z += (float)a[6]; hi.w += (float)a[7];
    *(float4*)(avg + i)     = lo;
    *(float4*)(avg + i + 4) = hi;
}

// ---------------------------------------------------------------------------
extern "C" void kernel_launch(void* const* d_in, const int* in_sizes, int n_in,
                              void* d_out, int out_size, void* d_ws, size_t ws_size,
                              hipStream_t stream)
{
    const float* query     = (const float*)d_in[0];
    const float* attn_bias = (const float*)d_in[1];
    const int*   mask      = (const int*)d_in[2];
    const float* q_w       = (const float*)d_in[3];
    const float* q_b       = (const float*)d_in[4];
    const float* k_w       = (const float*)d_in[5];
    const float* k_b       = (const float*)d_in[6];
    const float* v_w       = (const float*)d_in[7];
    const float* v_b       = (const float*)d_in[8];
    const float* out_w     = (const float*)d_in[9];
    const float* out_b     = (const float*)d_in[10];

    float* out     = (float*)d_out;                 // [1024,4,512]
    float* avg_out = out + (size_t)2097152;         // [4,1024,1024]

    char* wsb = (char*)d_ws;
    __bf16* Wqb   = (__bf16*)(wsb);                         // 512 KB
    __bf16* Wkb   = (__bf16*)(wsb + ((size_t)512 << 10));
    __bf16* Wvb   = (__bf16*)(wsb + ((size_t)1 << 20));
    __bf16* Wob   = (__bf16*)(wsb + ((size_t)1 << 20) + ((size_t)512 << 10));
    __bf16* qTb   = (__bf16*)(wsb + ((size_t)2  << 20));    // 4 MB [64][1024][32]
    __bf16* kTb   = (__bf16*)(wsb + ((size_t)6  << 20));    // 4 MB [64][1024][32]
    __bf16* vTb   = (__bf16*)(wsb + ((size_t)10 << 20));    // 4 MB [64][32][1024]
    __bf16* attnb = (__bf16*)(wsb + ((size_t)14 << 20));    // 4 MB [4096][512]
    __bf16* p1    = (__bf16*)(wsb + ((size_t)18 << 20));    // 8 MB

    cvt_w<<<dim3(128, 4), dim3(256), 0, stream>>>(
        q_w, k_w, v_w, out_w, Wqb, Wkb, Wvb, Wob);

    qkv_proj<<<dim3(64, 4, 3), dim3(256), 0, stream>>>(
        query, Wqb, Wkb, Wvb, q_b, k_b, v_b, qTb, kTb, vTb);

    attn_mfma<<<dim3(32, 4, 2), dim3(512), 0, stream>>>(
        qTb, kTb, vTb, attn_bias, mask, attnb, avg_out, p1);

    avg_add<<<dim3(2048), dim3(256), 0, stream>>>(avg_out, p1);

    out_proj<<<dim3(64, 4), dim3(256), 0, stream>>>(attnb, Wob, out_b, out);
}

// Round 7
// 164.240 us; speedup vs baseline: 1.9037x; 1.9037x over previous
//
#include <hip/hip_runtime.h>
#include <math.h>

typedef __bf16 bf16x8 __attribute__((ext_vector_type(8)));
typedef __bf16 bf16x4 __attribute__((ext_vector_type(4)));
typedef float  f32x4  __attribute__((ext_vector_type(4)));

// lgkmcnt(0) only: vmcnt=63 (bits[3:0]=0xF,[15:14]=0x3), expcnt=7, lgkmcnt=0
#define WAIT_LGKM0() __builtin_amdgcn_s_waitcnt(0xC07F)

// ---------------------------------------------------------------------------
// cvt: fp32 -> bf16 for the 4 weight matrices (512x512 each)
// ---------------------------------------------------------------------------
__global__ __launch_bounds__(256)
void cvt_w(const float* __restrict__ w0, const float* __restrict__ w1,
           const float* __restrict__ w2, const float* __restrict__ w3,
           __bf16* __restrict__ d0, __bf16* __restrict__ d1,
           __bf16* __restrict__ d2, __bf16* __restrict__ d3)
{
    const int y = blockIdx.y;
    const float* s = (y == 0) ? w0 : (y == 1) ? w1 : (y == 2) ? w2 : w3;
    __bf16*      d = (y == 0) ? d0 : (y == 1) ? d1 : (y == 2) ? d2 : d3;
    const int i = blockIdx.x * 256 + threadIdx.x;
    float4 a = *(const float4*)(s + (size_t)i * 8);
    float4 b = *(const float4*)(s + (size_t)i * 8 + 4);
    bf16x8 v;
    v[0] = (__bf16)a.x; v[1] = (__bf16)a.y; v[2] = (__bf16)a.z; v[3] = (__bf16)a.w;
    v[4] = (__bf16)b.x; v[5] = (__bf16)b.y; v[6] = (__bf16)b.z; v[7] = (__bf16)b.w;
    *(bf16x8*)(d + (size_t)i * 8) = v;
}

// ---------------------------------------------------------------------------
// Fused QKV projection. X fp32 (cvt on load), W bf16. Tile 64(M)x128(N).
// ---------------------------------------------------------------------------
__global__ __launch_bounds__(256)
void qkv_proj(const float* __restrict__ X,
              const __bf16* __restrict__ Wqb, const __bf16* __restrict__ Wkb,
              const __bf16* __restrict__ Wvb,
              const float* __restrict__ bq, const float* __restrict__ bk,
              const float* __restrict__ bv,
              __bf16* __restrict__ qTb, __bf16* __restrict__ kTb,
              __bf16* __restrict__ vTb)
{
    const int z = blockIdx.z;
    const __bf16* Wb   = (z == 0) ? Wqb : (z == 1) ? Wkb : Wvb;
    const float*  bias = (z == 0) ? bq  : (z == 1) ? bk  : bv;

    const int tid  = threadIdx.x;
    const int w    = tid >> 6;
    const int lane = tid & 63;
    const int lq   = lane & 15;
    const int quad = lane >> 4;
    const int n0    = blockIdx.x * 64 + (w >> 1) * 32;
    const int obase = blockIdx.y * 128 + (w & 1) * 64;

    f32x4 acc[2][4] = {};
#pragma unroll 2
    for (int k0 = 0; k0 < 512; k0 += 32) {
        bf16x8 af[2], bfr[4];
#pragma unroll
        for (int m = 0; m < 2; m++) {
            const float* xp = X + (size_t)(n0 + m * 16 + lq) * 512 + k0 + quad * 8;
            float4 x0 = *(const float4*)xp;
            float4 x1 = *(const float4*)(xp + 4);
            bf16x8 v;
            v[0] = (__bf16)x0.x; v[1] = (__bf16)x0.y; v[2] = (__bf16)x0.z; v[3] = (__bf16)x0.w;
            v[4] = (__bf16)x1.x; v[5] = (__bf16)x1.y; v[6] = (__bf16)x1.z; v[7] = (__bf16)x1.w;
            af[m] = v;
        }
#pragma unroll
        for (int nn = 0; nn < 4; nn++)
            bfr[nn] = *(const bf16x8*)(Wb + (size_t)(obase + nn * 16 + lq) * 512 + k0 + quad * 8);
#pragma unroll
        for (int m = 0; m < 2; m++)
#pragma unroll
            for (int nn = 0; nn < 4; nn++)
                acc[m][nn] = __builtin_amdgcn_mfma_f32_16x16x32_bf16(af[m], bfr[nn], acc[m][nn], 0, 0, 0);
    }

    const float scaling = 0.17677669529663687f;
#pragma unroll
    for (int m = 0; m < 2; m++)
#pragma unroll
        for (int nn = 0; nn < 4; nn++)
#pragma unroll
            for (int r = 0; r < 4; r++) {
                const int n = n0 + m * 16 + quad * 4 + r;
                const int o = obase + nn * 16 + lq;
                float val = acc[m][nn][r] + bias[o];
                const int t = n >> 2, b = n & 3;
                const int h = o >> 5, d = o & 31;
                const int bh = b * 16 + h;
                if (z == 0)
                    qTb[(((size_t)bh * 1024 + t) << 5) + d] = (__bf16)(val * scaling);
                else if (z == 1)
                    kTb[(((size_t)bh * 1024 + t) << 5) + d] = (__bf16)val;
                else
                    vTb[(((size_t)bh * 32 + d) << 10) + t] = (__bf16)val;
            }
}

// ---------------------------------------------------------------------------
// Out projection: A bf16 [4096][512], W bf16, out fp32 + bias. Tile 64x128.
// ---------------------------------------------------------------------------
__global__ __launch_bounds__(256)
void out_proj(const __bf16* __restrict__ A, const __bf16* __restrict__ Wb,
              const float* __restrict__ bias, float* __restrict__ out)
{
    const int tid  = threadIdx.x;
    const int w    = tid >> 6;
    const int lane = tid & 63;
    const int lq   = lane & 15;
    const int quad = lane >> 4;
    const int n0    = blockIdx.x * 64 + (w >> 1) * 32;
    const int obase = blockIdx.y * 128 + (w & 1) * 64;

    f32x4 acc[2][4] = {};
#pragma unroll 2
    for (int k0 = 0; k0 < 512; k0 += 32) {
        bf16x8 af[2], bfr[4];
#pragma unroll
        for (int m = 0; m < 2; m++)
            af[m] = *(const bf16x8*)(A + (size_t)(n0 + m * 16 + lq) * 512 + k0 + quad * 8);
#pragma unroll
        for (int nn = 0; nn < 4; nn++)
            bfr[nn] = *(const bf16x8*)(Wb + (size_t)(obase + nn * 16 + lq) * 512 + k0 + quad * 8);
#pragma unroll
        for (int m = 0; m < 2; m++)
#pragma unroll
            for (int nn = 0; nn < 4; nn++)
                acc[m][nn] = __builtin_amdgcn_mfma_f32_16x16x32_bf16(af[m], bfr[nn], acc[m][nn], 0, 0, 0);
    }
#pragma unroll
    for (int m = 0; m < 2; m++)
#pragma unroll
        for (int nn = 0; nn < 4; nn++)
#pragma unroll
            for (int r = 0; r < 4; r++) {
                const int n = n0 + m * 16 + quad * 4 + r;
                const int o = obase + nn * 16 + lq;
                out[(size_t)n * 512 + o] = acc[m][nn][r] + bias[o];
            }
}

// ---------------------------------------------------------------------------
// MFMA attention, 16 heads per block, grid (64,4) = 256 blocks = 1/CU.
//
// THE POINT OF THIS ROUND: registers. R6's counters exposed that the AMDGPU
// backend caps VGPRs from LDS-derived occupancy: at 68 KB LDS it targets
// 2 blocks/CU -> 4 waves/EU -> 128 VGPRs (observed VGPR_Count=128), while
// the loop's live set is ~160-190 -> per-head spill/refill traffic (R6:
// WRITE_SIZE 268 MB vs ~28 MB of real output). Every round since R2 ran in
// that straitjacket, which is why schedule/cache/occupancy experiments were
// all null. Fix: LDS deliberately >80 KB (one block/CU) + waves_per_eu(2,2)
// -> 256-VGPR budget, no spills; spend the headroom on a K double-buffer so
// K(h+1) prefetches alongside qa/cj(h+1) and the post-barrier QK waits on
// loads issued a full head earlier. V is issued just-in-time; its L2 hit
// hides under QK+exp. vmcnt discipline as proven in R2 (prefetch youngest,
// lgkm-only barrier, Op/red double-buffer).
// ---------------------------------------------------------------------------
__global__ __attribute__((amdgpu_waves_per_eu(2, 2))) __launch_bounds__(512)
void attn_mfma(const __bf16* __restrict__ qTb, const __bf16* __restrict__ kTb,
               const __bf16* __restrict__ vTb, const float* __restrict__ bias,
               const int* __restrict__ mask, __bf16* __restrict__ attnb,
               float* __restrict__ avgf)
{
    // [0,8448): Op[2][8][528]  [8448,8704): red[2][8][16]
    // [8704,17408): P bf16 [8][16*136]
    // Declared 20800 floats = 83,200 B > 80 KB on purpose: forces the
    // backend's LDS-occupancy target to 1 block/CU -> 256-VGPR allocation.
    __shared__ float smem[20800];
    float* const Op0  = smem;
    float* const red0 = &smem[8448];
    __bf16* const Pbase = (__bf16*)&smem[8704];

    const int tid  = threadIdx.x;
    const int w    = tid >> 6;
    const int lane = tid & 63;
    const int lq   = lane & 15;
    const int quad = lane >> 4;

    // bijective XCD swizzle: 256 blocks -> 32-block contiguous chunk per XCD
    const int bid = blockIdx.y * 64 + blockIdx.x;
    const int nb  = (bid & 7) * 32 + (bid >> 3);
    const int t0  = (nb & 63) * 16;
    const int b   = nb >> 6;
    const int sbase = w * 128;

    __bf16* const Pw = Pbase + w * 2176;   // 16*136 bf16 per wave

    // pack 32 mask bits (s = sbase + j*16 + quad*4 + r)
    unsigned mbits = 0;
    {
        const int* mp = mask + b * 1024 + sbase + quad * 4;
#pragma unroll
        for (int j = 0; j < 8; j++) {
            int4 m4 = *(const int4*)(mp + j * 16);
            mbits |= (unsigned)(m4.x != 0) << (j * 4 + 0);
            mbits |= (unsigned)(m4.y != 0) << (j * 4 + 1);
            mbits |= (unsigned)(m4.z != 0) << (j * 4 + 2);
            mbits |= (unsigned)(m4.w != 0) << (j * 4 + 3);
        }
    }

    // per-lane bases
    const float* const bb = bias + (((size_t)(b * 16)) << 20) +
                            (((size_t)(t0 + lq)) << 10) + sbase + quad * 4;
    const __bf16* const qp0 = qTb + (((size_t)(b * 16) * 1024 + t0) << 5) +
                              lq * 32 + quad * 8;
    const __bf16* const kp0 = kTb + ((size_t)(b * 16) << 15);
    const __bf16* const vp0 = vTb + ((size_t)(b * 16) << 15);

    // prologue: head 0 K + Q + bias into registers
    bf16x8 kbA[8], kbB[8];
#pragma unroll
    for (int j = 0; j < 8; j++)
        kbA[j] = *(const bf16x8*)(kp0 + (size_t)(sbase + j * 16 + lq) * 32 + quad * 8);
    bf16x8 qa = *(const bf16x8*)qp0;
    f32x4 cj[8];
#pragma unroll
    for (int j = 0; j < 8; j++) cj[j] = *(const f32x4*)(bb + j * 16);

    float avg_reg[32] = {};
    bf16x8 v0r[4], v1r[4];

    // head body: kcur holds K(hh) (loaded last iteration); prefetches K/Q/cj
    // for head hh+1 into knext. Static kbA/kbB alternation (no runtime
    // indexing -> no scratch).
    auto head_body = [&](bf16x8 (&kcur)[8], bf16x8 (&knext)[8], int hh) {
        float* const Op  = Op0  + (hh & 1) * 4224;
        float* const red = red0 + (hh & 1) * 128;
        const __bf16* vp = vp0 + ((size_t)hh << 15);

        // V for THIS head, just-in-time (younger than kcur/qa/cj, so the QK
        // waits below do not drain it; consumed at PV after QK+exp cover
        // its L2 latency).
#pragma unroll
        for (int ks = 0; ks < 4; ks++) {
            v0r[ks] = *(const bf16x8*)(vp + (size_t)lq * 1024 + sbase + ks * 32 + quad * 8);
            v1r[ks] = *(const bf16x8*)(vp + (size_t)(16 + lq) * 1024 + sbase + ks * 32 + quad * 8);
        }
        __builtin_amdgcn_sched_barrier(0);

        // QK: kcur/qa/cj were issued one full head ago -> complete; no stall.
        f32x4 acc[8];
        __builtin_amdgcn_s_setprio(1);
#pragma unroll
        for (int j = 0; j < 8; j++)
            acc[j] = __builtin_amdgcn_mfma_f32_16x16x32_bf16(kcur[j], qa, cj[j], 0, 0, 0);
        __builtin_amdgcn_s_setprio(0);
        __builtin_amdgcn_sched_barrier(0);

        // prefetch next head's K + Q + bias: youngest VMEM of this head;
        // nothing younger is waited on until QK(h+1). Branchless wrap.
        {
            const int hn = (hh + 1) & 15;
            const __bf16* kpn = kp0 + ((size_t)hn << 15);
#pragma unroll
            for (int j = 0; j < 8; j++)
                knext[j] = *(const bf16x8*)(kpn + (size_t)(sbase + j * 16 + lq) * 32 + quad * 8);
            qa = *(const bf16x8*)(qp0 + ((size_t)hn << 15));
            const float* bn = bb + ((size_t)hn << 20);
#pragma unroll
            for (int j = 0; j < 8; j++) cj[j] = *(const f32x4*)(bn + j * 16);
        }
        __builtin_amdgcn_sched_barrier(0);

        // exp (no max pass; scores bounded) + mask + row partial sum
        float sm = 0.f;
#pragma unroll
        for (int j = 0; j < 8; j++)
#pragma unroll
            for (int r = 0; r < 4; r++) {
                float p = __expf(acc[j][r]);
                p = ((mbits >> (j * 4 + r)) & 1u) ? 0.f : p;
                acc[j][r] = p;
                sm += p;
            }
        sm += __shfl_xor(sm, 16);
        sm += __shfl_xor(sm, 32);

        // unnormalized bf16 P into per-wave LDS region (same-wave use only)
#pragma unroll
        for (int j = 0; j < 8; j++) {
            bf16x4 pv;
            pv[0] = (__bf16)acc[j][0]; pv[1] = (__bf16)acc[j][1];
            pv[2] = (__bf16)acc[j][2]; pv[3] = (__bf16)acc[j][3];
            *(bf16x4*)&Pw[lq * 136 + j * 16 + quad * 4] = pv;
        }
        if (lane < 16) red[w * 16 + lane] = sm;

        // PV: P from LDS (lgkmcnt only), V in registers
        f32x4 o0 = {0.f, 0.f, 0.f, 0.f}, o1 = {0.f, 0.f, 0.f, 0.f};
        __builtin_amdgcn_s_setprio(1);
#pragma unroll
        for (int ks = 0; ks < 4; ks++) {
            bf16x8 pa = *(const bf16x8*)&Pw[lq * 136 + ks * 32 + quad * 8];
            o0 = __builtin_amdgcn_mfma_f32_16x16x32_bf16(pa, v0r[ks], o0, 0, 0, 0);
            o1 = __builtin_amdgcn_mfma_f32_16x16x32_bf16(pa, v1r[ks], o1, 0, 0, 0);
        }
        __builtin_amdgcn_s_setprio(0);
#pragma unroll
        for (int r = 0; r < 4; r++) {
            Op[w * 528 + (quad * 4 + r) * 33 + lq]      = o0[r];
            Op[w * 528 + (quad * 4 + r) * 33 + 16 + lq] = o1[r];
        }

        // raw barrier: compiler fence + lgkm-only drain; prefetch stays live.
        __builtin_amdgcn_sched_barrier(0);
        asm volatile("" ::: "memory");
        WAIT_LGKM0();
        __builtin_amdgcn_s_barrier();
        asm volatile("" ::: "memory");
        __builtin_amdgcn_sched_barrier(0);

        // cross-wave reduce: normalized O write
        {
            const int t = tid >> 5, d = tid & 31;
            float s = 0.f, o = 0.f;
#pragma unroll
            for (int w2 = 0; w2 < 8; w2++) s += red[w2 * 16 + t];
#pragma unroll
            for (int w2 = 0; w2 < 8; w2++) o += Op[w2 * 528 + t * 33 + d];
            attnb[((size_t)(t0 + t) * 4 + b) * 512 + hh * 32 + d] = (__bf16)(o / s);
        }

        // inv for this lane's rows (t = lq) + avg fold; acc dies here
        float s_all = 0.f;
#pragma unroll
        for (int w2 = 0; w2 < 8; w2++) s_all += red[w2 * 16 + lq];
        const float inv = 1.0f / s_all;
#pragma unroll
        for (int j = 0; j < 8; j++)
#pragma unroll
            for (int r = 0; r < 4; r++)
                avg_reg[j * 4 + r] += acc[j][r] * inv;
    };

    for (int hp = 0; hp < 8; hp++) {
        head_body(kbA, kbB, hp * 2);
        head_body(kbB, kbA, hp * 2 + 1);
    }

    // head-mean store: single fp32 write (all 16 heads accumulated here)
    float* ap = avgf + ((size_t)(b * 1024 + t0 + lq) << 10) + sbase + quad * 4;
#pragma unroll
    for (int j = 0; j < 8; j++) {
        f32x4 v = { avg_reg[j * 4 + 0] * 0.0625f, avg_reg[j * 4 + 1] * 0.0625f,
                    avg_reg[j * 4 + 2] * 0.0625f, avg_reg[j * 4 + 3] * 0.0625f };
        *(f32x4*)(ap + j * 16) = v;
    }
}

// ---------------------------------------------------------------------------
extern "C" void kernel_launch(void* const* d_in, const int* in_sizes, int n_in,
                              void* d_out, int out_size, void* d_ws, size_t ws_size,
                              hipStream_t stream)
{
    const float* query     = (const float*)d_in[0];
    const float* attn_bias = (const float*)d_in[1];
    const int*   mask      = (const int*)d_in[2];
    const float* q_w       = (const float*)d_in[3];
    const float* q_b       = (const float*)d_in[4];
    const float* k_w       = (const float*)d_in[5];
    const float* k_b       = (const float*)d_in[6];
    const float* v_w       = (const float*)d_in[7];
    const float* v_b       = (const float*)d_in[8];
    const float* out_w     = (const float*)d_in[9];
    const float* out_b     = (const float*)d_in[10];

    float* out     = (float*)d_out;                 // [1024,4,512]
    float* avg_out = out + (size_t)2097152;         // [4,1024,1024]

    char* wsb = (char*)d_ws;
    __bf16* Wqb   = (__bf16*)(wsb);                         // 512 KB
    __bf16* Wkb   = (__bf16*)(wsb + ((size_t)512 << 10));
    __bf16* Wvb   = (__bf16*)(wsb + ((size_t)1 << 20));
    __bf16* Wob   = (__bf16*)(wsb + ((size_t)1 << 20) + ((size_t)512 << 10));
    __bf16* qTb   = (__bf16*)(wsb + ((size_t)2  << 20));    // 4 MB [64][1024][32]
    __bf16* kTb   = (__bf16*)(wsb + ((size_t)6  << 20));    // 4 MB [64][1024][32]
    __bf16* vTb   = (__bf16*)(wsb + ((size_t)10 << 20));    // 4 MB [64][32][1024]
    __bf16* attnb = (__bf16*)(wsb + ((size_t)14 << 20));    // 4 MB [4096][512]

    cvt_w<<<dim3(128, 4), dim3(256), 0, stream>>>(
        q_w, k_w, v_w, out_w, Wqb, Wkb, Wvb, Wob);

    qkv_proj<<<dim3(64, 4, 3), dim3(256), 0, stream>>>(
        query, Wqb, Wkb, Wvb, q_b, k_b, v_b, qTb, kTb, vTb);

    attn_mfma<<<dim3(64, 4), dim3(512), 0, stream>>>(
        qTb, kTb, vTb, attn_bias, mask, attnb, avg_out);

    out_proj<<<dim3(64, 4), dim3(256), 0, stream>>>(attnb, Wob, out_b, out);
}

// Round 8
// 149.388 us; speedup vs baseline: 2.0929x; 1.0994x over previous
//
#include <hip/hip_runtime.h>
#include <math.h>

typedef __bf16 bf16x8 __attribute__((ext_vector_type(8)));
typedef __bf16 bf16x4 __attribute__((ext_vector_type(4)));
typedef float  f32x4  __attribute__((ext_vector_type(4)));

// ---------------------------------------------------------------------------
// cvt: fp32 -> bf16 for the 4 weight matrices (512x512 each)
// ---------------------------------------------------------------------------
__global__ __launch_bounds__(256)
void cvt_w(const float* __restrict__ w0, const float* __restrict__ w1,
           const float* __restrict__ w2, const float* __restrict__ w3,
           __bf16* __restrict__ d0, __bf16* __restrict__ d1,
           __bf16* __restrict__ d2, __bf16* __restrict__ d3)
{
    const int y = blockIdx.y;
    const float* s = (y == 0) ? w0 : (y == 1) ? w1 : (y == 2) ? w2 : w3;
    __bf16*      d = (y == 0) ? d0 : (y == 1) ? d1 : (y == 2) ? d2 : d3;
    const int i = blockIdx.x * 256 + threadIdx.x;
    float4 a = *(const float4*)(s + (size_t)i * 8);
    float4 b = *(const float4*)(s + (size_t)i * 8 + 4);
    bf16x8 v;
    v[0] = (__bf16)a.x; v[1] = (__bf16)a.y; v[2] = (__bf16)a.z; v[3] = (__bf16)a.w;
    v[4] = (__bf16)b.x; v[5] = (__bf16)b.y; v[6] = (__bf16)b.z; v[7] = (__bf16)b.w;
    *(bf16x8*)(d + (size_t)i * 8) = v;
}

// ---------------------------------------------------------------------------
// Fused QKV projection, z-merged: ONE block computes Q, K and V outputs for
// its (x,y) tile. X (fp32, cvt on load) is loaded ONCE per k-chunk and feeds
// all three MFMA sets -> X issue 96->8 MB, W issue 96->~36 MB, cvt VALU /3.
// acc[3][2][4] = 96 VGPR; __launch_bounds__(256,2) pins the 256-VGPR budget
// (2 blocks/CU, no LDS). Tile 64(M)x128(N) as before.
// ---------------------------------------------------------------------------
__global__ __launch_bounds__(256, 2)
void qkv_proj(const float* __restrict__ X,
              const __bf16* __restrict__ Wqb, const __bf16* __restrict__ Wkb,
              const __bf16* __restrict__ Wvb,
              const float* __restrict__ bq, const float* __restrict__ bk,
              const float* __restrict__ bv,
              __bf16* __restrict__ qTb, __bf16* __restrict__ kTb,
              __bf16* __restrict__ vTb)
{
    const int tid  = threadIdx.x;
    const int w    = tid >> 6;
    const int lane = tid & 63;
    const int lq   = lane & 15;
    const int quad = lane >> 4;
    const int n0    = blockIdx.x * 64 + (w >> 1) * 32;
    const int obase = blockIdx.y * 128 + (w & 1) * 64;

    const __bf16* const Wz[3] = { Wqb, Wkb, Wvb };

    f32x4 acc[3][2][4] = {};
    for (int k0 = 0; k0 < 512; k0 += 32) {
        bf16x8 af[2];
#pragma unroll
        for (int m = 0; m < 2; m++) {
            const float* xp = X + (size_t)(n0 + m * 16 + lq) * 512 + k0 + quad * 8;
            float4 x0 = *(const float4*)xp;
            float4 x1 = *(const float4*)(xp + 4);
            bf16x8 v;
            v[0] = (__bf16)x0.x; v[1] = (__bf16)x0.y; v[2] = (__bf16)x0.z; v[3] = (__bf16)x0.w;
            v[4] = (__bf16)x1.x; v[5] = (__bf16)x1.y; v[6] = (__bf16)x1.z; v[7] = (__bf16)x1.w;
            af[m] = v;
        }
#pragma unroll
        for (int z = 0; z < 3; z++) {
            bf16x8 bfr[4];
#pragma unroll
            for (int nn = 0; nn < 4; nn++)
                bfr[nn] = *(const bf16x8*)(Wz[z] + (size_t)(obase + nn * 16 + lq) * 512 + k0 + quad * 8);
#pragma unroll
            for (int m = 0; m < 2; m++)
#pragma unroll
                for (int nn = 0; nn < 4; nn++)
                    acc[z][m][nn] = __builtin_amdgcn_mfma_f32_16x16x32_bf16(af[m], bfr[nn], acc[z][m][nn], 0, 0, 0);
        }
    }

    const float* const ba[3] = { bq, bk, bv };
    const float scaling = 0.17677669529663687f;
#pragma unroll
    for (int z = 0; z < 3; z++)
#pragma unroll
        for (int m = 0; m < 2; m++)
#pragma unroll
            for (int nn = 0; nn < 4; nn++)
#pragma unroll
                for (int r = 0; r < 4; r++) {
                    const int n = n0 + m * 16 + quad * 4 + r;
                    const int o = obase + nn * 16 + lq;
                    float val = acc[z][m][nn][r] + ba[z][o];
                    const int t = n >> 2, b = n & 3;
                    const int h = o >> 5, d = o & 31;
                    const int bh = b * 16 + h;
                    if (z == 0)
                        qTb[(((size_t)bh * 1024 + t) << 5) + d] = (__bf16)(val * scaling);
                    else if (z == 1)
                        kTb[(((size_t)bh * 1024 + t) << 5) + d] = (__bf16)val;
                    else
                        vTb[(((size_t)bh * 32 + d) << 10) + t] = (__bf16)val;
                }
}

// ---------------------------------------------------------------------------
// Out projection: A bf16 [4096][512], W bf16, out fp32 + bias. Tile 64x128.
// ---------------------------------------------------------------------------
__global__ __launch_bounds__(256)
void out_proj(const __bf16* __restrict__ A, const __bf16* __restrict__ Wb,
              const float* __restrict__ bias, float* __restrict__ out)
{
    const int tid  = threadIdx.x;
    const int w    = tid >> 6;
    const int lane = tid & 63;
    const int lq   = lane & 15;
    const int quad = lane >> 4;
    const int n0    = blockIdx.x * 64 + (w >> 1) * 32;
    const int obase = blockIdx.y * 128 + (w & 1) * 64;

    f32x4 acc[2][4] = {};
    for (int k0 = 0; k0 < 512; k0 += 32) {
        bf16x8 af[2], bfr[4];
#pragma unroll
        for (int m = 0; m < 2; m++)
            af[m] = *(const bf16x8*)(A + (size_t)(n0 + m * 16 + lq) * 512 + k0 + quad * 8);
#pragma unroll
        for (int nn = 0; nn < 4; nn++)
            bfr[nn] = *(const bf16x8*)(Wb + (size_t)(obase + nn * 16 + lq) * 512 + k0 + quad * 8);
#pragma unroll
        for (int m = 0; m < 2; m++)
#pragma unroll
            for (int nn = 0; nn < 4; nn++)
                acc[m][nn] = __builtin_amdgcn_mfma_f32_16x16x32_bf16(af[m], bfr[nn], acc[m][nn], 0, 0, 0);
    }
#pragma unroll
    for (int m = 0; m < 2; m++)
#pragma unroll
        for (int nn = 0; nn < 4; nn++)
#pragma unroll
            for (int r = 0; r < 4; r++) {
                const int n = n0 + m * 16 + quad * 4 + r;
                const int o = obase + nn * 16 + lq;
                out[(size_t)n * 512 + o] = acc[m][nn][r] + bias[o];
            }
}

// ---------------------------------------------------------------------------
// MFMA attention, 16 heads per block. Block = (t-tile 16, b). 8 waves; wave w
// owns s in [w*128,+128). R2-exact (best measured config, 157.9us):
// VMEM order per head: [K x8 via QK][V x8 hoisted] | pin | [qa/bias prefetch
// = youngest] | pin | exp/P/PV; raw lgkm-only barrier; Op/red double-buffer;
// bias as register C-operands; single fp32 avg write.
// ---------------------------------------------------------------------------
__global__ __launch_bounds__(512, 2)
void attn_mfma(const __bf16* __restrict__ qTb, const __bf16* __restrict__ kTb,
               const __bf16* __restrict__ vTb, const float* __restrict__ bias,
               const int* __restrict__ mask, __bf16* __restrict__ attnb,
               float* __restrict__ avgf)
{
    // [0,8448): Op[2][8][528]  [8448,8704): red[2][8][16]
    // [8704,17408): P bf16 [8][16*136]
    __shared__ float smem[17408];
    float* const Op0  = smem;
    float* const red0 = &smem[8448];
    __bf16* const Pbase = (__bf16*)&smem[8704];

    const int tid  = threadIdx.x;
    const int w    = tid >> 6;
    const int lane = tid & 63;
    const int lq   = lane & 15;
    const int quad = lane >> 4;

    // bijective XCD swizzle: 256 blocks -> 32-block contiguous chunk per XCD
    const int bid = blockIdx.y * 64 + blockIdx.x;
    const int nb  = (bid & 7) * 32 + (bid >> 3);
    const int t0  = (nb & 63) * 16;
    const int b   = nb >> 6;
    const int sbase = w * 128;

    __bf16* const Pw = Pbase + w * 2176;   // 16*136 bf16 per wave

    // pack 32 mask bits (s = sbase + j*16 + quad*4 + r)
    unsigned mbits = 0;
    {
        const int* mp = mask + b * 1024 + sbase + quad * 4;
#pragma unroll
        for (int j = 0; j < 8; j++) {
            int4 m4 = *(const int4*)(mp + j * 16);
            mbits |= (unsigned)(m4.x != 0) << (j * 4 + 0);
            mbits |= (unsigned)(m4.y != 0) << (j * 4 + 1);
            mbits |= (unsigned)(m4.z != 0) << (j * 4 + 2);
            mbits |= (unsigned)(m4.w != 0) << (j * 4 + 3);
        }
    }

    // bias C-operand base for this lane: bias[bh][t0+lq][sbase + quad*4 + j*16]
    const float* const bb = bias + (((size_t)(b * 16)) << 20) +
                            (((size_t)(t0 + lq)) << 10) + sbase + quad * 4;
    const __bf16* const qp0 = qTb + (((size_t)(b * 16) * 1024 + t0) << 5) +
                              lq * 32 + quad * 8;

    // prologue: head 0 Q + bias into registers (q first, so QK's first wait
    // leaves cj[1..7] outstanding)
    bf16x8 qa = *(const bf16x8*)qp0;
    f32x4 cj[8];
#pragma unroll
    for (int j = 0; j < 8; j++) cj[j] = *(const f32x4*)(bb + j * 16);

    float avg_reg[32] = {};

    for (int hh = 0; hh < 16; hh++) {
        const int bh = b * 16 + hh;
        float* const Op  = Op0  + (hh & 1) * 4224;
        float* const red = red0 + (hh & 1) * 128;
        const __bf16* kp = kTb + ((size_t)bh << 15);
        const __bf16* vp = vTb + ((size_t)bh << 15);

        // QK: C-operand comes straight from the bias registers. The vmcnt
        // wait here is the ONLY consumption point of last head's prefetch.
        f32x4 acc[8];
#pragma unroll
        for (int j = 0; j < 8; j++) {
            bf16x8 kb = *(const bf16x8*)(kp + (size_t)(sbase + j * 16 + lq) * 32 + quad * 8);
            acc[j] = __builtin_amdgcn_mfma_f32_16x16x32_bf16(kb, qa, cj[j], 0, 0, 0);
        }

        // V loads for THIS head, hoisted ahead of the bias prefetch so every
        // later intra-head wait targets only loads OLDER than the prefetch.
        bf16x8 v0r[4], v1r[4];
#pragma unroll
        for (int ks = 0; ks < 4; ks++) {
            v0r[ks] = *(const bf16x8*)(vp + (size_t)lq * 1024 + sbase + ks * 32 + quad * 8);
            v1r[ks] = *(const bf16x8*)(vp + (size_t)(16 + lq) * 1024 + sbase + ks * 32 + quad * 8);
        }

        // pin: bias prefetch must not be scheduled above the V loads
        __builtin_amdgcn_sched_barrier(0);

        // prefetch next head's Q + bias now: youngest VMEM of this head, in
        // flight through exp/PV/reduce and across the raw barrier.
        if (hh < 15) {
            qa = *(const bf16x8*)(qp0 + ((size_t)(hh + 1) << 15));
            const float* bn = bb + ((size_t)(hh + 1) << 20);
#pragma unroll
            for (int j = 0; j < 8; j++) cj[j] = *(const f32x4*)(bn + j * 16);
        }

        // exp (no max pass; scores bounded) + mask + row partial sum
        float sm = 0.f;
#pragma unroll
        for (int j = 0; j < 8; j++)
#pragma unroll
            for (int r = 0; r < 4; r++) {
                float p = __expf(acc[j][r]);
                p = ((mbits >> (j * 4 + r)) & 1u) ? 0.f : p;
                acc[j][r] = p;
                sm += p;
            }
        sm += __shfl_xor(sm, 16);
        sm += __shfl_xor(sm, 32);

        // unnormalized bf16 P into per-wave LDS region (same-wave use only)
#pragma unroll
        for (int j = 0; j < 8; j++) {
            bf16x4 pv;
            pv[0] = (__bf16)acc[j][0]; pv[1] = (__bf16)acc[j][1];
            pv[2] = (__bf16)acc[j][2]; pv[3] = (__bf16)acc[j][3];
            *(bf16x4*)&Pw[lq * 136 + j * 16 + quad * 4] = pv;
        }
        if (lane < 16) red[w * 16 + lane] = sm;

        // PV: P from LDS (lgkmcnt only), V from registers (no VMEM waits)
        f32x4 o0 = {0.f, 0.f, 0.f, 0.f}, o1 = {0.f, 0.f, 0.f, 0.f};
#pragma unroll
        for (int ks = 0; ks < 4; ks++) {
            bf16x8 pa = *(const bf16x8*)&Pw[lq * 136 + ks * 32 + quad * 8];
            o0 = __builtin_amdgcn_mfma_f32_16x16x32_bf16(pa, v0r[ks], o0, 0, 0, 0);
            o1 = __builtin_amdgcn_mfma_f32_16x16x32_bf16(pa, v1r[ks], o1, 0, 0, 0);
        }
#pragma unroll
        for (int r = 0; r < 4; r++) {
            Op[w * 528 + (quad * 4 + r) * 33 + lq]      = o0[r];
            Op[w * 528 + (quad * 4 + r) * 33 + 16 + lq] = o1[r];
        }

        // raw barrier: drain LDS only; bias prefetch (VMEM) stays in flight.
        __builtin_amdgcn_sched_barrier(0);
        asm volatile("s_waitcnt lgkmcnt(0)" ::: "memory");
        __builtin_amdgcn_s_barrier();
        __builtin_amdgcn_sched_barrier(0);

        // cross-wave reduce: normalized O write
        {
            const int t = tid >> 5, d = tid & 31;
            float s = 0.f, o = 0.f;
#pragma unroll
            for (int w2 = 0; w2 < 8; w2++) s += red[w2 * 16 + t];
#pragma unroll
            for (int w2 = 0; w2 < 8; w2++) o += Op[w2 * 528 + t * 33 + d];
            attnb[((size_t)(t0 + t) * 4 + b) * 512 + hh * 32 + d] = (__bf16)(o / s);
        }

        // inv for this lane's rows (t = lq) + avg fold; acc dies here
        float s_all = 0.f;
#pragma unroll
        for (int w2 = 0; w2 < 8; w2++) s_all += red[w2 * 16 + lq];
        const float inv = 1.0f / s_all;
#pragma unroll
        for (int j = 0; j < 8; j++)
#pragma unroll
            for (int r = 0; r < 4; r++)
                avg_reg[j * 4 + r] += acc[j][r] * inv;
    }

    // head-mean store: single fp32 write (all 16 heads accumulated here)
    float* ap = avgf + ((size_t)(b * 1024 + t0 + lq) << 10) + sbase + quad * 4;
#pragma unroll
    for (int j = 0; j < 8; j++) {
        f32x4 v = { avg_reg[j * 4 + 0] * 0.0625f, avg_reg[j * 4 + 1] * 0.0625f,
                    avg_reg[j * 4 + 2] * 0.0625f, avg_reg[j * 4 + 3] * 0.0625f };
        *(f32x4*)(ap + j * 16) = v;
    }
}

// ---------------------------------------------------------------------------
extern "C" void kernel_launch(void* const* d_in, const int* in_sizes, int n_in,
                              void* d_out, int out_size, void* d_ws, size_t ws_size,
                              hipStream_t stream)
{
    const float* query     = (const float*)d_in[0];
    const float* attn_bias = (const float*)d_in[1];
    const int*   mask      = (const int*)d_in[2];
    const float* q_w       = (const float*)d_in[3];
    const float* q_b       = (const float*)d_in[4];
    const float* k_w       = (const float*)d_in[5];
    const float* k_b       = (const float*)d_in[6];
    const float* v_w       = (const float*)d_in[7];
    const float* v_b       = (const float*)d_in[8];
    const float* out_w     = (const float*)d_in[9];
    const float* out_b     = (const float*)d_in[10];

    float* out     = (float*)d_out;                 // [1024,4,512]
    float* avg_out = out + (size_t)2097152;         // [4,1024,1024]

    char* wsb = (char*)d_ws;
    __bf16* Wqb   = (__bf16*)(wsb);                         // 512 KB
    __bf16* Wkb   = (__bf16*)(wsb + ((size_t)512 << 10));
    __bf16* Wvb   = (__bf16*)(wsb + ((size_t)1 << 20));
    __bf16* Wob   = (__bf16*)(wsb + ((size_t)1 << 20) + ((size_t)512 << 10));
    __bf16* qTb   = (__bf16*)(wsb + ((size_t)2  << 20));    // 4 MB [64][1024][32]
    __bf16* kTb   = (__bf16*)(wsb + ((size_t)6  << 20));    // 4 MB [64][1024][32]
    __bf16* vTb   = (__bf16*)(wsb + ((size_t)10 << 20));    // 4 MB [64][32][1024]
    __bf16* attnb = (__bf16*)(wsb + ((size_t)14 << 20));    // 4 MB [4096][512]

    cvt_w<<<dim3(128, 4), dim3(256), 0, stream>>>(
        q_w, k_w, v_w, out_w, Wqb, Wkb, Wvb, Wob);

    qkv_proj<<<dim3(64, 4), dim3(256), 0, stream>>>(
        query, Wqb, Wkb, Wvb, q_b, k_b, v_b, qTb, kTb, vTb);

    attn_mfma<<<dim3(64, 4), dim3(512), 0, stream>>>(
        qTb, kTb, vTb, attn_bias, mask, attnb, avg_out);

    out_proj<<<dim3(64, 4), dim3(256), 0, stream>>>(attnb, Wob, out_b, out);
}

// Round 9
// 145.101 us; speedup vs baseline: 2.1547x; 1.0295x over previous
//
#include <hip/hip_runtime.h>
#include <math.h>

typedef __bf16 bf16x8 __attribute__((ext_vector_type(8)));
typedef __bf16 bf16x4 __attribute__((ext_vector_type(4)));
typedef float  f32x4  __attribute__((ext_vector_type(4)));

// ---------------------------------------------------------------------------
// cvt: fp32 -> bf16 for the 4 weight matrices (512x512 each)
// ---------------------------------------------------------------------------
__global__ __launch_bounds__(256)
void cvt_w(const float* __restrict__ w0, const float* __restrict__ w1,
           const float* __restrict__ w2, const float* __restrict__ w3,
           __bf16* __restrict__ d0, __bf16* __restrict__ d1,
           __bf16* __restrict__ d2, __bf16* __restrict__ d3)
{
    const int y = blockIdx.y;
    const float* s = (y == 0) ? w0 : (y == 1) ? w1 : (y == 2) ? w2 : w3;
    __bf16*      d = (y == 0) ? d0 : (y == 1) ? d1 : (y == 2) ? d2 : d3;
    const int i = blockIdx.x * 256 + threadIdx.x;
    float4 a = *(const float4*)(s + (size_t)i * 8);
    float4 b = *(const float4*)(s + (size_t)i * 8 + 4);
    bf16x8 v;
    v[0] = (__bf16)a.x; v[1] = (__bf16)a.y; v[2] = (__bf16)a.z; v[3] = (__bf16)a.w;
    v[4] = (__bf16)b.x; v[5] = (__bf16)b.y; v[6] = (__bf16)b.z; v[7] = (__bf16)b.w;
    *(bf16x8*)(d + (size_t)i * 8) = v;
}

// ---------------------------------------------------------------------------
// Fused QKV projection, z-merged (R8-proven, +9us): one block computes Q, K
// and V for its tile; X loaded once per k-chunk feeds all three MFMA sets.
// ---------------------------------------------------------------------------
__global__ __launch_bounds__(256, 2)
void qkv_proj(const float* __restrict__ X,
              const __bf16* __restrict__ Wqb, const __bf16* __restrict__ Wkb,
              const __bf16* __restrict__ Wvb,
              const float* __restrict__ bq, const float* __restrict__ bk,
              const float* __restrict__ bv,
              __bf16* __restrict__ qTb, __bf16* __restrict__ kTb,
              __bf16* __restrict__ vTb)
{
    const int tid  = threadIdx.x;
    const int w    = tid >> 6;
    const int lane = tid & 63;
    const int lq   = lane & 15;
    const int quad = lane >> 4;
    const int n0    = blockIdx.x * 64 + (w >> 1) * 32;
    const int obase = blockIdx.y * 128 + (w & 1) * 64;

    const __bf16* const Wz[3] = { Wqb, Wkb, Wvb };

    f32x4 acc[3][2][4] = {};
    for (int k0 = 0; k0 < 512; k0 += 32) {
        bf16x8 af[2];
#pragma unroll
        for (int m = 0; m < 2; m++) {
            const float* xp = X + (size_t)(n0 + m * 16 + lq) * 512 + k0 + quad * 8;
            float4 x0 = *(const float4*)xp;
            float4 x1 = *(const float4*)(xp + 4);
            bf16x8 v;
            v[0] = (__bf16)x0.x; v[1] = (__bf16)x0.y; v[2] = (__bf16)x0.z; v[3] = (__bf16)x0.w;
            v[4] = (__bf16)x1.x; v[5] = (__bf16)x1.y; v[6] = (__bf16)x1.z; v[7] = (__bf16)x1.w;
            af[m] = v;
        }
#pragma unroll
        for (int z = 0; z < 3; z++) {
            bf16x8 bfr[4];
#pragma unroll
            for (int nn = 0; nn < 4; nn++)
                bfr[nn] = *(const bf16x8*)(Wz[z] + (size_t)(obase + nn * 16 + lq) * 512 + k0 + quad * 8);
#pragma unroll
            for (int m = 0; m < 2; m++)
#pragma unroll
                for (int nn = 0; nn < 4; nn++)
                    acc[z][m][nn] = __builtin_amdgcn_mfma_f32_16x16x32_bf16(af[m], bfr[nn], acc[z][m][nn], 0, 0, 0);
        }
    }

    const float* const ba[3] = { bq, bk, bv };
    const float scaling = 0.17677669529663687f;
#pragma unroll
    for (int z = 0; z < 3; z++)
#pragma unroll
        for (int m = 0; m < 2; m++)
#pragma unroll
            for (int nn = 0; nn < 4; nn++)
#pragma unroll
                for (int r = 0; r < 4; r++) {
                    const int n = n0 + m * 16 + quad * 4 + r;
                    const int o = obase + nn * 16 + lq;
                    float val = acc[z][m][nn][r] + ba[z][o];
                    const int t = n >> 2, b = n & 3;
                    const int h = o >> 5, d = o & 31;
                    const int bh = b * 16 + h;
                    if (z == 0)
                        qTb[(((size_t)bh * 1024 + t) << 5) + d] = (__bf16)(val * scaling);
                    else if (z == 1)
                        kTb[(((size_t)bh * 1024 + t) << 5) + d] = (__bf16)val;
                    else
                        vTb[(((size_t)bh * 32 + d) << 10) + t] = (__bf16)val;
                }
}

// ---------------------------------------------------------------------------
// Out projection: A bf16 [4096][512], W bf16, out fp32 + bias. Tile 64x128.
// ---------------------------------------------------------------------------
__global__ __launch_bounds__(256)
void out_proj(const __bf16* __restrict__ A, const __bf16* __restrict__ Wb,
              const float* __restrict__ bias, float* __restrict__ out)
{
    const int tid  = threadIdx.x;
    const int w    = tid >> 6;
    const int lane = tid & 63;
    const int lq   = lane & 15;
    const int quad = lane >> 4;
    const int n0    = blockIdx.x * 64 + (w >> 1) * 32;
    const int obase = blockIdx.y * 128 + (w & 1) * 64;

    f32x4 acc[2][4] = {};
    for (int k0 = 0; k0 < 512; k0 += 32) {
        bf16x8 af[2], bfr[4];
#pragma unroll
        for (int m = 0; m < 2; m++)
            af[m] = *(const bf16x8*)(A + (size_t)(n0 + m * 16 + lq) * 512 + k0 + quad * 8);
#pragma unroll
        for (int nn = 0; nn < 4; nn++)
            bfr[nn] = *(const bf16x8*)(Wb + (size_t)(obase + nn * 16 + lq) * 512 + k0 + quad * 8);
#pragma unroll
        for (int m = 0; m < 2; m++)
#pragma unroll
            for (int nn = 0; nn < 4; nn++)
                acc[m][nn] = __builtin_amdgcn_mfma_f32_16x16x32_bf16(af[m], bfr[nn], acc[m][nn], 0, 0, 0);
    }
#pragma unroll
    for (int m = 0; m < 2; m++)
#pragma unroll
        for (int nn = 0; nn < 4; nn++)
#pragma unroll
            for (int r = 0; r < 4; r++) {
                const int n = n0 + m * 16 + quad * 4 + r;
                const int o = obase + nn * 16 + lq;
                out[(size_t)n * 512 + o] = acc[m][nn][r] + bias[o];
            }
}

// ---------------------------------------------------------------------------
// MFMA attention, K/V register reuse (R6 geometry) under the R7 register
// environment. Block = (32 t-rows, b, 8-head half); grid (32,4,2) = 256
// blocks = 1/CU. K/V for a head loaded ONCE into registers and reused for
// both 16-row t-subtiles -> issued K/V traffic halves (512 -> 256 MB), the
// remaining lever after R3/R4/R5/R7 falsified everything else: the attn
// phase is limited by total L2/L3-fabric traffic (~770 MB at ~7 TB/s ==
// the measured ~110 us), not by HBM (R6: FETCH == bias only).
//
// R6's failure was the 128-VGPR cap (68 KB LDS -> 2-block residency
// target) spilling the ~230-reg live set (240 MB scratch traffic). Fix per
// R7: LDS > 80 KB + waves_per_eu(2,2) -> 1 block/CU -> 256-VGPR budget.
// Static ts via two lambda calls (no runtime-indexed register arrays).
// Inner schedule is R2/R6-exact: bias as register C-operands, qa/cj
// prefetch youngest VMEM, lgkm-only raw barrier, Op/red double-buffer.
// ---------------------------------------------------------------------------
__global__ __attribute__((amdgpu_waves_per_eu(2, 2))) __launch_bounds__(512)
void attn_mfma(const __bf16* __restrict__ qTb, const __bf16* __restrict__ kTb,
               const __bf16* __restrict__ vTb, const float* __restrict__ bias,
               const int* __restrict__ mask, __bf16* __restrict__ attnb,
               float* __restrict__ avgf, __bf16* __restrict__ p1)
{
    // [0,8448): Op[2][8][528]  [8448,8704): red[2][8][16]
    // [8704,17408): P bf16 [8][16*136]
    // Declared 20800 floats = 83,200 B > 80 KB on purpose: 1 block/CU
    // residency target -> 256-VGPR allocation (R7-proven trick).
    __shared__ float smem[20800];
    float* const Op0  = smem;
    float* const red0 = &smem[8448];
    __bf16* const Pbase = (__bf16*)&smem[8704];

    const int tid  = threadIdx.x;
    const int w    = tid >> 6;
    const int lane = tid & 63;
    const int lq   = lane & 15;
    const int quad = lane >> 4;

    // bijective XCD swizzle (R6-verified): per XCD one contiguous 32-block
    // chunk = one (z,b) pair x all t-supertiles -> per-XCD hot K/V ~1 MB.
    const int bid = blockIdx.z * 128 + blockIdx.y * 32 + blockIdx.x;
    const int swz = (bid & 7) * 32 + (bid >> 3);
    const int t0  = (swz & 31) * 32;       // 32-row t-supertile
    const int b   = (swz >> 5) & 3;
    const int z   = swz >> 7;              // head half
    const int sbase = w * 128;

    __bf16* const Pw = Pbase + w * 2176;   // 16*136 bf16 per wave

    // pack 32 mask bits (s = sbase + j*16 + quad*4 + r); s-only, shared by
    // both t-subtiles
    unsigned mbits = 0;
    {
        const int* mp = mask + b * 1024 + sbase + quad * 4;
#pragma unroll
        for (int j = 0; j < 8; j++) {
            int4 m4 = *(const int4*)(mp + j * 16);
            mbits |= (unsigned)(m4.x != 0) << (j * 4 + 0);
            mbits |= (unsigned)(m4.y != 0) << (j * 4 + 1);
            mbits |= (unsigned)(m4.z != 0) << (j * 4 + 2);
            mbits |= (unsigned)(m4.w != 0) << (j * 4 + 3);
        }
    }

    // bases for this block's 8 heads (z*8 .. z*8+7), t-rows t0..t0+31
    const float* const bb = bias + (((size_t)(b * 16 + z * 8)) << 20) +
                            (((size_t)(t0 + lq)) << 10) + sbase + quad * 4;
    const __bf16* const qp0 = qTb + (((size_t)((b * 16 + z * 8) * 1024 + t0)) << 5) +
                              lq * 32 + quad * 8;
    const __bf16* const kp0 = kTb + ((size_t)(b * 16 + z * 8) << 15);
    const __bf16* const vp0 = vTb + ((size_t)(b * 16 + z * 8) << 15);

    // prologue: (head 0, ts 0) Q + bias into registers
    bf16x8 qa = *(const bf16x8*)qp0;
    f32x4 cj[8];
#pragma unroll
    for (int j = 0; j < 8; j++) cj[j] = *(const f32x4*)(bb + j * 16);

    float avg0[32] = {}, avg1[32] = {};
    bf16x8 kb[8];            // persist across the two t-subtiles of a head
    bf16x8 v0r[4], v1r[4];

    // body for one (head, t-subtile). ts is a call-site literal -> fully
    // constant-folded (static register indexing, rule-of-thumb #20).
    auto body = [&](int hh, int ts, float (&avg)[32]) {
        float* const Op  = Op0  + ts * 4224;       // ts alternates 0/1
        float* const red = red0 + ts * 128;

        // K/V for this head: loaded once (ts==0), reused at ts==1.
        if (ts == 0) {
            const __bf16* kp = kp0 + ((size_t)hh << 15);
            const __bf16* vp = vp0 + ((size_t)hh << 15);
#pragma unroll
            for (int j = 0; j < 8; j++)
                kb[j] = *(const bf16x8*)(kp + (size_t)(sbase + j * 16 + lq) * 32 + quad * 8);
#pragma unroll
            for (int ks = 0; ks < 4; ks++) {
                v0r[ks] = *(const bf16x8*)(vp + (size_t)lq * 1024 + sbase + ks * 32 + quad * 8);
                v1r[ks] = *(const bf16x8*)(vp + (size_t)(16 + lq) * 1024 + sbase + ks * 32 + quad * 8);
            }
        }
        __builtin_amdgcn_sched_barrier(0);

        // QK: bias C-operands from registers (prefetched last iteration)
        f32x4 acc[8];
#pragma unroll
        for (int j = 0; j < 8; j++)
            acc[j] = __builtin_amdgcn_mfma_f32_16x16x32_bf16(kb[j], qa, cj[j], 0, 0, 0);
        __builtin_amdgcn_sched_barrier(0);

        // prefetch next iteration's Q + bias (youngest VMEM; wraps benignly)
        {
            const int hn  = (ts == 0) ? hh : ((hh + 1) & 7);
            const int tsn = ts ^ 1;
            qa = *(const bf16x8*)(qp0 + ((size_t)hn << 15) + (tsn << 9));
            const float* bn = bb + ((size_t)hn << 20) + (tsn << 14);
#pragma unroll
            for (int j = 0; j < 8; j++) cj[j] = *(const f32x4*)(bn + j * 16);
        }
        __builtin_amdgcn_sched_barrier(0);

        // exp (no max pass; scores bounded) + mask + row partial sum
        float sm = 0.f;
#pragma unroll
        for (int j = 0; j < 8; j++)
#pragma unroll
            for (int r = 0; r < 4; r++) {
                float p = __expf(acc[j][r]);
                p = ((mbits >> (j * 4 + r)) & 1u) ? 0.f : p;
                acc[j][r] = p;
                sm += p;
            }
        sm += __shfl_xor(sm, 16);
        sm += __shfl_xor(sm, 32);

        // unnormalized bf16 P into per-wave LDS region (same-wave use only)
#pragma unroll
        for (int j = 0; j < 8; j++) {
            bf16x4 pv;
            pv[0] = (__bf16)acc[j][0]; pv[1] = (__bf16)acc[j][1];
            pv[2] = (__bf16)acc[j][2]; pv[3] = (__bf16)acc[j][3];
            *(bf16x4*)&Pw[lq * 136 + j * 16 + quad * 4] = pv;
        }
        if (lane < 16) red[w * 16 + lane] = sm;

        // PV: P from LDS (lgkmcnt only), V in registers
        f32x4 o0 = {0.f, 0.f, 0.f, 0.f}, o1 = {0.f, 0.f, 0.f, 0.f};
#pragma unroll
        for (int ks = 0; ks < 4; ks++) {
            bf16x8 pa = *(const bf16x8*)&Pw[lq * 136 + ks * 32 + quad * 8];
            o0 = __builtin_amdgcn_mfma_f32_16x16x32_bf16(pa, v0r[ks], o0, 0, 0, 0);
            o1 = __builtin_amdgcn_mfma_f32_16x16x32_bf16(pa, v1r[ks], o1, 0, 0, 0);
        }
#pragma unroll
        for (int r = 0; r < 4; r++) {
            Op[w * 528 + (quad * 4 + r) * 33 + lq]      = o0[r];
            Op[w * 528 + (quad * 4 + r) * 33 + 16 + lq] = o1[r];
        }

        // raw barrier: compiler fence + lgkm-only drain; prefetch stays live.
        __builtin_amdgcn_sched_barrier(0);
        asm volatile("s_waitcnt lgkmcnt(0)" ::: "memory");
        __builtin_amdgcn_s_barrier();
        __builtin_amdgcn_sched_barrier(0);

        // cross-wave reduce: normalized O write
        {
            const int t = tid >> 5, d = tid & 31;
            float s = 0.f, o = 0.f;
#pragma unroll
            for (int w2 = 0; w2 < 8; w2++) s += red[w2 * 16 + t];
#pragma unroll
            for (int w2 = 0; w2 < 8; w2++) o += Op[w2 * 528 + t * 33 + d];
            attnb[((size_t)(t0 + ts * 16 + t) * 4 + b) * 512 + (z * 8 + hh) * 32 + d] =
                (__bf16)(o / s);
        }

        // inv for this lane's rows (t = ts*16+lq) + avg fold; acc dies here
        float s_all = 0.f;
#pragma unroll
        for (int w2 = 0; w2 < 8; w2++) s_all += red[w2 * 16 + lq];
        const float inv = 1.0f / s_all;
#pragma unroll
        for (int j = 0; j < 8; j++)
#pragma unroll
            for (int r = 0; r < 4; r++)
                avg[j * 4 + r] += acc[j][r] * inv;
    };

    for (int hh = 0; hh < 8; hh++) {
        body(hh, 0, avg0);
        body(hh, 1, avg1);
    }

    // head-mean stores for both t-subtiles: z=0 fp32 direct, z=1 bf16 partial
#pragma unroll
    for (int ts = 0; ts < 2; ts++) {
        const float* avg = ts ? avg1 : avg0;
        const size_t rowbase = ((size_t)(b * 1024 + t0 + ts * 16 + lq) << 10) +
                               sbase + quad * 4;
        if (z == 0) {
            float* ap = avgf + rowbase;
#pragma unroll
            for (int j = 0; j < 8; j++) {
                f32x4 v = { avg[j * 4 + 0] * 0.0625f, avg[j * 4 + 1] * 0.0625f,
                            avg[j * 4 + 2] * 0.0625f, avg[j * 4 + 3] * 0.0625f };
                *(f32x4*)(ap + j * 16) = v;
            }
        } else {
            __bf16* pp = p1 + rowbase;
#pragma unroll
            for (int j = 0; j < 8; j++) {
                bf16x4 v;
                v[0] = (__bf16)(avg[j * 4 + 0] * 0.0625f);
                v[1] = (__bf16)(avg[j * 4 + 1] * 0.0625f);
                v[2] = (__bf16)(avg[j * 4 + 2] * 0.0625f);
                v[3] = (__bf16)(avg[j * 4 + 3] * 0.0625f);
                *(bf16x4*)(pp + j * 16) = v;
            }
        }
    }
}

// avg_out += p1 (bf16 partial). 2048 blocks * 256 thr * 8 = 4194304
__global__ __launch_bounds__(256)
void avg_add(float* __restrict__ avg, const __bf16* __restrict__ p1)
{
    const size_t i = ((size_t)blockIdx.x * 256 + threadIdx.x) * 8;
    bf16x8 a = *(const bf16x8*)(p1 + i);
    float4 lo = *(float4*)(avg + i);
    float4 hi = *(float4*)(avg + i + 4);
    lo.x += (float)a[0]; lo.y += (float)a[1];
    lo.z += (float)a[2]; lo.w += (float)a[3];
    hi.x += (float)a[4]; hi.y += (float)a[5];
    hi.z += (float)a[6]; hi.w += (float)a[7];
    *(float4*)(avg + i)     = lo;
    *(float4*)(avg + i + 4) = hi;
}

// ---------------------------------------------------------------------------
extern "C" void kernel_launch(void* const* d_in, const int* in_sizes, int n_in,
                              void* d_out, int out_size, void* d_ws, size_t ws_size,
                              hipStream_t stream)
{
    const float* query     = (const float*)d_in[0];
    const float* attn_bias = (const float*)d_in[1];
    const int*   mask      = (const int*)d_in[2];
    const float* q_w       = (const float*)d_in[3];
    const float* q_b       = (const float*)d_in[4];
    const float* k_w       = (const float*)d_in[5];
    const float* k_b       = (const float*)d_in[6];
    const float* v_w       = (const float*)d_in[7];
    const float* v_b       = (const float*)d_in[8];
    const float* out_w     = (const float*)d_in[9];
    const float* out_b     = (const float*)d_in[10];

    float* out     = (float*)d_out;                 // [1024,4,512]
    float* avg_out = out + (size_t)2097152;         // [4,1024,1024]

    char* wsb = (char*)d_ws;
    __bf16* Wqb   = (__bf16*)(wsb);                         // 512 KB
    __bf16* Wkb   = (__bf16*)(wsb + ((size_t)512 << 10));
    __bf16* Wvb   = (__bf16*)(wsb + ((size_t)1 << 20));
    __bf16* Wob   = (__bf16*)(wsb + ((size_t)1 << 20) + ((size_t)512 << 10));
    __bf16* qTb   = (__bf16*)(wsb + ((size_t)2  << 20));    // 4 MB [64][1024][32]
    __bf16* kTb   = (__bf16*)(wsb + ((size_t)6  << 20));    // 4 MB [64][1024][32]
    __bf16* vTb   = (__bf16*)(wsb + ((size_t)10 << 20));    // 4 MB [64][32][1024]
    __bf16* attnb = (__bf16*)(wsb + ((size_t)14 << 20));    // 4 MB [4096][512]
    __bf16* p1    = (__bf16*)(wsb + ((size_t)18 << 20));    // 8 MB

    cvt_w<<<dim3(128, 4), dim3(256), 0, stream>>>(
        q_w, k_w, v_w, out_w, Wqb, Wkb, Wvb, Wob);

    qkv_proj<<<dim3(64, 4), dim3(256), 0, stream>>>(
        query, Wqb, Wkb, Wvb, q_b, k_b, v_b, qTb, kTb, vTb);

    attn_mfma<<<dim3(32, 4, 2), dim3(512), 0, stream>>>(
        qTb, kTb, vTb, attn_bias, mask, attnb, avg_out, p1);

    avg_add<<<dim3(2048), dim3(256), 0, stream>>>(avg_out, p1);

    out_proj<<<dim3(64, 4), dim3(256), 0, stream>>>(attnb, Wob, out_b, out);
}